// Round 14
// baseline (51430.267 us; speedup 1.0000x reference)
//
#include <hip/hip_runtime.h>
#include <hip/hip_cooperative_groups.h>

namespace cg = cooperative_groups;

// 2-layer LSTM, S=512, B=32, H=1024, E=512.
// Round 14: r13 champion + batch split 2 -> 4 groups of 8 rows.
// Grid 512 blocks (2/CU, __launch_bounds__(512,4) pins VGPR<=128 = what the
// compiler already allocates). Per group: private 128-block pipeline
// (64 L0 + 64 L1), verbatim r12/r13 protocol (subset polls, 3-barrier L0,
// ring depth 4/2, full flag1 guards). MFMA M=16 runs half-filled (rows 8-15
// duplicate rows 0-7; outputs discarded) - per-row arithmetic identical.

#define S_LEN 512
#define BATCH 32
#define HID   1024
#define EMB   512
#define NBLK  512
#define NTHR  512
#define RB    8      // rows per group

typedef short  bf16x8 __attribute__((ext_vector_type(8)));
typedef float  f32x4  __attribute__((ext_vector_type(4)));

union U8 { bf16x8 v; unsigned short us[8]; uint4 u4; unsigned long long ull[2]; };

__device__ __forceinline__ unsigned short f2bf(float f) {   // RNE f32->bf16
    unsigned u = __float_as_uint(f);
    u += 0x7fffu + ((u >> 16) & 1u);
    return (unsigned short)(u >> 16);
}

__device__ __forceinline__ uint4 pack8(float4 lo, float4 hi) {
    U8 r;
    r.us[0] = f2bf(lo.x); r.us[1] = f2bf(lo.y); r.us[2] = f2bf(lo.z); r.us[3] = f2bf(lo.w);
    r.us[4] = f2bf(hi.x); r.us[5] = f2bf(hi.y); r.us[6] = f2bf(hi.z); r.us[7] = f2bf(hi.w);
    return r.u4;
}

__device__ __forceinline__ f32x4 mfma16(bf16x8 a, bf16x8 b, f32x4 c) {
    return __builtin_amdgcn_mfma_f32_16x16x32_bf16(a, b, c, 0, 0, 0);
}

// agent-scope (LLC-coherent, L2-bypass) 16B load/store as 2x8B atomics
__device__ __forceinline__ U8 ld_ws16(const uint4* p) {
    const unsigned long long* q = (const unsigned long long*)p;
    U8 r;
    r.ull[0] = __hip_atomic_load(q,     __ATOMIC_RELAXED, __HIP_MEMORY_SCOPE_AGENT);
    r.ull[1] = __hip_atomic_load(q + 1, __ATOMIC_RELAXED, __HIP_MEMORY_SCOPE_AGENT);
    return r;
}
__device__ __forceinline__ void st_ws16(uint4* p, U8 v) {
    unsigned long long* q = (unsigned long long*)p;
    __hip_atomic_store(q,     v.ull[0], __ATOMIC_RELAXED, __HIP_MEMORY_SCOPE_AGENT);
    __hip_atomic_store(q + 1, v.ull[1], __ATOMIC_RELAXED, __HIP_MEMORY_SCOPE_AGENT);
}

__device__ __forceinline__ float sigm(float x) {
    return __builtin_amdgcn_rcpf(1.0f + __expf(-x));
}
__device__ __forceinline__ float tanh_fast(float x) {
    const float xc = fminf(fmaxf(x, -15.f), 15.f);
    const float t  = __expf(2.f * xc);
    return (t - 1.f) * __builtin_amdgcn_rcpf(t + 1.f);
}

// full poll: lane l watches flags[l*16]; exit when ALL >= target
__device__ __forceinline__ void poll64(const int* flags, int target) {
    const int* p = flags + ((threadIdx.x & 63) << 4);
    for (;;) {
        const int v = __hip_atomic_load(p, __ATOMIC_RELAXED, __HIP_MEMORY_SCOPE_AGENT);
        if (__all(v >= target)) break;
        __builtin_amdgcn_s_sleep(1);
    }
}
// subset poll: watch flags[base..base+cnt) (lanes >= cnt duplicate base)
__device__ __forceinline__ void pollsub(const int* flags, int base, int cnt, int target) {
    const int l   = threadIdx.x & 63;
    const int idx = (l < cnt) ? l : 0;
    const int* p  = flags + ((base + idx) << 4);
    for (;;) {
        const int v = __hip_atomic_load(p, __ATOMIC_RELAXED, __HIP_MEMORY_SCOPE_AGENT);
        if (__all(v >= target)) break;
        __builtin_amdgcn_s_sleep(1);
    }
}

__global__ __launch_bounds__(NTHR, 4)
void lstm_pipe(const int* __restrict__ x, const float* __restrict__ embed,
               const float* __restrict__ Wi0, const float* __restrict__ Wh0,
               const float* __restrict__ bi0, const float* __restrict__ bh0,
               const float* __restrict__ Wi1, const float* __restrict__ Wh1,
               const float* __restrict__ bi1, const float* __restrict__ bh1,
               const float* __restrict__ h0in, const float* __restrict__ c0in,
               float* __restrict__ outputs, float* __restrict__ hiddens,
               float* __restrict__ cells, uint4* __restrict__ ws)
{
    __shared__ f32x4 sRed[8][4][64];               // 32KB
    __shared__ uint4 sEmb[64 * 9];                 // 9.2KB (L0 only; RB=8 +1 pad)
    __shared__ float sGates[16][68];               // rows 8-15 written, unused
    __shared__ unsigned short sHex[RB][16];
    __shared__ float sBias[16][4];

    const int tid  = threadIdx.x;
    const int lane = tid & 63;
    const int wv   = tid >> 6;                     // 0..7 = K-split wave
    const int bx   = blockIdx.x;
    const int grp  = bx >> 7;                      // 0..3 = batch-row group
    const int gbx  = bx & 127;
    const bool isL0 = (gbx < 64);
    const int g    = isL0 ? gbx : gbx - 64;        // column-block id 0..63

    // ws (uint4 units) per group: h0 ring 4x1024 | h1 ring 2x1024  (=6144)
    // unit index = (kg8<<3)+b : 8 bf16 h-cols kg8*8.. for group-row b(0..7).
    uint4* h0base = ws + grp * 6144;
    uint4* h1base = h0base + 4096;
    int*   fbase  = (int*)(ws + 24576) + grp * 2048;   // flag0[64],flag1[64] @64B
    int*   flag0  = fbase;
    int*   flag1  = fbase + 1024;

    // ---- prepass: zero flags, init h tiles ----
    {
        const int gt = bx * NTHR + tid;
        if (gt < 8192) ((int*)(ws + 24576))[gt] = 0;
        const int gt2 = gt - 65536;                // disjoint index range
        if (gt2 >= 0 && gt2 < 8192) {              // 4 grp x 2 layer x 128 kg x 8 b
            const int b = gt2 & 7, kg8 = (gt2 >> 3) & 127;
            const int layer = (gt2 >> 10) & 1, gg = gt2 >> 11;
            const float* src = h0in + ((size_t)((layer << 5) + (gg << 3) + b)) * HID + (kg8 << 3);
            uint4* dst = ws + gg * 6144 + (layer ? (4096 + 1024) : (3 * 1024));
            dst[(kg8 << 3) + b] = pack8(*(const float4*)src, *(const float4*)(src + 4));
        }
    }
    if (tid < 16) {
        #pragma unroll
        for (int gate = 0; gate < 4; ++gate) {
            const int r = (gate << 10) + (g << 4) + tid;
            sBias[tid][gate] = isL0 ? (bi0[r] + bh0[r]) : (bi1[r] + bh1[r]);
        }
    }
    const int pjj = tid & 15;                      // column (tid<128)
    const int pb  = (tid >> 4) & 7;                // group-local row (tid<128)
    const int jg  = (g << 4) + pjj;
    const int growbase = grp * RB;                 // global row = growbase + pb
    float creg = 0.f;
    if (tid < 128)
        creg = c0in[(size_t)((isL0 ? 0 : BATCH) + growbase + pb) * HID + jg];

    // ---- weight B-fragments into registers (verified layout) ----
    const int n_  = lane & 15;
    const int ko_ = (lane >> 4) << 3;
    const int rb_ = ((n_ >> 2) << 10) + (g << 4) + (n_ & 3);
    bf16x8 w0[4][6];
    bf16x8 w1[4][8];
    if (isL0) {
        #pragma unroll
        for (int nt = 0; nt < 4; ++nt) {
            const int r = rb_ + (nt << 2);
            #pragma unroll
            for (int kf = 0; kf < 6; ++kf) {
                const int k = wv * 192 + kf * 32 + ko_;
                const float* src = (k < EMB) ? Wi0 + (size_t)r * EMB + k
                                             : Wh0 + (size_t)r * HID + (k - EMB);
                U8 t; t.u4 = pack8(*(const float4*)src, *(const float4*)(src + 4));
                w0[nt][kf] = t.v;
            }
        }
    } else {
        #pragma unroll
        for (int nt = 0; nt < 4; ++nt) {
            const int r = rb_ + (nt << 2);
            #pragma unroll
            for (int kf = 0; kf < 8; ++kf) {
                const int k = (wv << 8) + kf * 32 + ko_;
                const float* src = (k < HID) ? Wi1 + (size_t)r * HID + k
                                             : Wh1 + (size_t)r * HID + (k - HID);
                U8 t; t.u4 = pack8(*(const float4*)src, *(const float4*)(src + 4));
                w1[nt][kf] = t.v;
            }
        }
    }

    // ---- L0 prologue: stage sEmb(0); pe = emb(1). row b = wv (one/wave) ----
    float4 pe0, pe1;
    if (isL0) {
        {
            const float* src = embed + (size_t)x[growbase + wv] * EMB + (lane << 3);
            sEmb[lane * 9 + wv] = pack8(*(const float4*)src, *(const float4*)(src + 4));
        }
        {
            const float* src = embed + (size_t)x[32 + growbase + wv] * EMB + (lane << 3);
            pe0 = *(const float4*)src;
            pe1 = *(const float4*)(src + 4);
        }
    }

    cg::grid_group grid = cg::this_grid();
    grid.sync();                                   // publish prepass, once

    const size_t BH = (size_t)BATCH * HID;

    if (isL0) {
        // ======================= LAYER-0 BLOCKS =======================
        for (int s = 0; s < S_LEN; ++s) {
            // subset poll + h-tile loads (waves 2..7; waves 0-1 pure emb)
            U8 r0[6];
            if (wv >= 2) {
                const int fst = (wv * 6 < 16) ? 16 : wv * 6;
                const int pb0 = (fst - 16) << 1;
                const int pct = ((wv * 6 + 6 - 16) << 1) - pb0;
                pollsub(flag0, pb0, pct, s);       // h0(s-1) fresh: flag0>=s
                const uint4* h0p = h0base + (((s + 3) & 3) << 10);
                #pragma unroll
                for (int kf = 0; kf < 6; ++kf) {
                    const int kfg = wv * 6 + kf;
                    if (kfg >= 16) {
                        const int u = ((((kfg - 16) << 2) + (lane >> 4)) << 3) + (lane & 7);
                        r0[kf] = ld_ws16(&h0p[u]);
                    }
                }
            }
            // MFMA (M=16 half-filled: rows 8-15 duplicate 0-7, discarded)
            f32x4 acc[4] = {{0,0,0,0},{0,0,0,0},{0,0,0,0},{0,0,0,0}};
            #pragma unroll
            for (int kf = 0; kf < 6; ++kf) {
                const int kfg = wv * 6 + kf;
                bf16x8 a0;
                if (kfg < 16) {
                    const int u = ((kfg << 2) + (lane >> 4)) * 9 + (lane & 7);
                    U8 t0; t0.u4 = sEmb[u]; a0 = t0.v;
                } else {
                    a0 = r0[kf].v;
                }
                #pragma unroll
                for (int nt = 0; nt < 4; ++nt)
                    acc[nt] = mfma16(a0, w0[nt][kf], acc[nt]);
            }
            #pragma unroll
            for (int nt = 0; nt < 4; ++nt)
                sRed[wv][nt][lane] = acc[nt];
            __syncthreads();                       // B1: sRed ready, sEmb reads done

            // stage sEmb(s+1); issue pe(s+2); reduce  (B1..B2 window)
            if (s + 1 < S_LEN)
                sEmb[lane * 9 + wv] = pack8(pe0, pe1);
            if (s + 2 < S_LEN) {
                const float* src = embed + (size_t)x[((s + 2) << 5) + growbase + wv] * EMB + (lane << 3);
                pe0 = *(const float4*)src;
                pe1 = *(const float4*)(src + 4);
            }
            if (tid < 256) {                       // K-split reduce (4 N-tiles)
                const int nt = tid >> 6, l = tid & 63;
                f32x4 sum = sRed[0][nt][l];
                #pragma unroll
                for (int w = 1; w < 8; ++w) sum += sRed[w][nt][l];
                const int b0 = (l >> 4) << 2;
                const int col = (nt << 4) + (l & 15);
                sGates[b0 + 0][col] = sum[0];
                sGates[b0 + 1][col] = sum[1];
                sGates[b0 + 2][col] = sum[2];
                sGates[b0 + 3][col] = sum[3];
            }
            __syncthreads();                       // B2: gates + sEmb(s+1) ready

            float cn_out = 0.f, hn_out = 0.f;
            if (tid < 128) {                       // pointwise (8x16 values)
                const int cb = ((pjj >> 2) << 4) + (pjj & 3);
                const float ii = sigm     (sGates[pb][cb]      + sBias[pjj][0]);
                const float ff = sigm     (sGates[pb][cb + 4]  + sBias[pjj][1]);
                const float gg = tanh_fast(sGates[pb][cb + 8]  + sBias[pjj][2]);
                const float oo = sigm     (sGates[pb][cb + 12] + sBias[pjj][3]);
                cn_out = ff * creg + ii * gg;
                creg = cn_out;
                hn_out = oo * tanh_fast(cn_out);
                sHex[pb][pjj] = f2bf(hn_out);
            }
            __syncthreads();                       // B3: sHex ready

            if (wv == 0) {                         // publish h0(s)
                if (s >= 4) poll64(flag1, s - 3);  // FULL ring-overwrite guard
                if (lane < 16) {                   // 2 kg8 x 8 rows = 16 units
                    const int b = lane & 7, kgl = lane >> 3;
                    U8 hb;
                    #pragma unroll
                    for (int jj = 0; jj < 8; ++jj) hb.us[jj] = sHex[b][(kgl << 3) + jj];
                    st_ws16(h0base + ((s & 3) << 10) + (((g << 1) + kgl) << 3) + b, hb);
                }
                asm volatile("s_waitcnt vmcnt(0)" ::: "memory");
                if (lane == 0)
                    __hip_atomic_store(flag0 + (g << 4), s + 1,
                                       __ATOMIC_RELAXED, __HIP_MEMORY_SCOPE_AGENT);
            }
            // d_out off the critical path
            if (tid < 128) {
                const size_t o = (size_t)(growbase + pb) * HID + jg;
                cells  [(size_t)(s << 1) * BH + o] = cn_out;
                hiddens[(size_t)(s << 1) * BH + o] = hn_out;
            }
        }
    } else {
        // ======================= LAYER-1 BLOCKS =======================
        for (int s = 0; s < S_LEN; ++s) {
            // waves 0-3: subset poll of their 16 h0 publishers;
            // waves 4-7: FULL flag1 poll (depth-2 h1 overwrite proof)
            if (wv < 4) pollsub(flag0, wv << 4, 16, s + 1);
            else        poll64(flag1, s);

            const uint4* h0c = h0base + ((s & 3) << 10);
            const uint4* h1p = h1base + (((s + 1) & 1) << 10);
            U8 r0[8];
            #pragma unroll
            for (int kf = 0; kf < 8; ++kf) {
                const int kfg = (wv << 3) + kf;
                const uint4* src = (kfg < 32) ? h0c : h1p;
                const int u = ((((kfg & 31) << 2) + (lane >> 4)) << 3) + (lane & 7);
                r0[kf] = ld_ws16(&src[u]);
            }
            f32x4 acc[4] = {{0,0,0,0},{0,0,0,0},{0,0,0,0},{0,0,0,0}};
            #pragma unroll
            for (int kf = 0; kf < 8; ++kf) {
                #pragma unroll
                for (int nt = 0; nt < 4; ++nt)
                    acc[nt] = mfma16(r0[kf].v, w1[nt][kf], acc[nt]);
            }
            #pragma unroll
            for (int nt = 0; nt < 4; ++nt)
                sRed[wv][nt][lane] = acc[nt];
            __syncthreads();
            if (tid < 256) {
                const int nt = tid >> 6, l = tid & 63;
                f32x4 sum = sRed[0][nt][l];
                #pragma unroll
                for (int w = 1; w < 8; ++w) sum += sRed[w][nt][l];
                const int b0 = (l >> 4) << 2;
                const int col = (nt << 4) + (l & 15);
                sGates[b0 + 0][col] = sum[0];
                sGates[b0 + 1][col] = sum[1];
                sGates[b0 + 2][col] = sum[2];
                sGates[b0 + 3][col] = sum[3];
            }
            __syncthreads();
            float cn_out = 0.f, hn_out = 0.f;
            if (tid < 128) {                       // pointwise
                const int cb = ((pjj >> 2) << 4) + (pjj & 3);
                const float ii = sigm     (sGates[pb][cb]      + sBias[pjj][0]);
                const float ff = sigm     (sGates[pb][cb + 4]  + sBias[pjj][1]);
                const float gg = tanh_fast(sGates[pb][cb + 8]  + sBias[pjj][2]);
                const float oo = sigm     (sGates[pb][cb + 12] + sBias[pjj][3]);
                cn_out = ff * creg + ii * gg;
                creg = cn_out;
                hn_out = oo * tanh_fast(cn_out);
                sHex[pb][pjj] = f2bf(hn_out);
            }
            __syncthreads();
            if (wv == 0) {                         // publish h1(s)
                if (lane < 16) {
                    const int b = lane & 7, kgl = lane >> 3;
                    U8 hb;
                    #pragma unroll
                    for (int jj = 0; jj < 8; ++jj) hb.us[jj] = sHex[b][(kgl << 3) + jj];
                    st_ws16(h1base + ((s & 1) << 10) + (((g << 1) + kgl) << 3) + b, hb);
                }
                asm volatile("s_waitcnt vmcnt(0)" ::: "memory");
                if (lane == 0)
                    __hip_atomic_store(flag1 + (g << 4), s + 1,
                                       __ATOMIC_RELAXED, __HIP_MEMORY_SCOPE_AGENT);
            }
            // d_out off the critical path
            if (tid < 128) {
                const size_t o = (size_t)(growbase + pb) * HID + jg;
                cells  [(size_t)((s << 1) + 1) * BH + o] = cn_out;
                hiddens[(size_t)((s << 1) + 1) * BH + o] = hn_out;
                outputs[(size_t)s * BH + o]              = hn_out;
            }
        }
    }
}

// ---------------- fallback: verified round-0 per-step kernel ----------------
#define KC 256
__global__ __launch_bounds__(256)
void lstm_step(const float* __restrict__ Wi, const float* __restrict__ Wh,
               const float* __restrict__ bi, const float* __restrict__ bh,
               const float* __restrict__ xsrc, const int* __restrict__ xidx, int K1,
               const float* __restrict__ Hprev, const float* __restrict__ Cprev,
               float* __restrict__ Hout, float* __restrict__ Cout,
               float* __restrict__ Hout2)
{
    __shared__ float As[32][KC + 4];
    __shared__ float red[256][5];

    const int t  = threadIdx.x;
    const int b  = t & 31;
    const int jl = (t >> 5) & 1;
    const int ks = t >> 6;
    const int j  = (blockIdx.x << 1) + jl;

    const int Ktot = K1 + HID;
    const int NC   = Ktot / KC;

    float acc0 = 0.f, acc1 = 0.f, acc2 = 0.f, acc3 = 0.f;

    for (int c = 0; c < NC; ++c) {
        const int  k0  = c * KC;
        const bool isX = (k0 < K1);

        #pragma unroll
        for (int i = 0; i < 8; ++i) {
            const int idx4 = t + (i << 8);
            const int row  = idx4 >> 6;
            const int c4   = idx4 & 63;
            const float* src;
            if (isX) {
                const size_t r0 = xidx ? (size_t)xidx[row] : (size_t)row;
                src = xsrc + r0 * (size_t)K1 + k0;
            } else {
                src = Hprev + (size_t)row * HID + (k0 - K1);
            }
            *(float4*)&As[row][c4 << 2] = *(const float4*)(src + (c4 << 2));
        }
        __syncthreads();

        const float* W      = isX ? Wi : Wh;
        const int    stride = isX ? K1 : HID;
        const int    kw     = k0 + (ks << 6) - (isX ? 0 : K1);
        const float* w0 = W + (size_t)(j       ) * stride + kw;
        const float* w1 = W + (size_t)(j + 1024) * stride + kw;
        const float* w2 = W + (size_t)(j + 2048) * stride + kw;
        const float* w3 = W + (size_t)(j + 3072) * stride + kw;
        const float* a  = &As[b][ks << 6];

        #pragma unroll 4
        for (int kk = 0; kk < 64; kk += 4) {
            const float4 av = *(const float4*)(a + kk);
            float4 w;
            w = *(const float4*)(w0 + kk);
            acc0 = fmaf(av.x, w.x, acc0); acc0 = fmaf(av.y, w.y, acc0);
            acc0 = fmaf(av.z, w.z, acc0); acc0 = fmaf(av.w, w.w, acc0);
            w = *(const float4*)(w1 + kk);
            acc1 = fmaf(av.x, w.x, acc1); acc1 = fmaf(av.y, w.y, acc1);
            acc1 = fmaf(av.z, w.z, acc1); acc1 = fmaf(av.w, w.w, acc1);
            w = *(const float4*)(w2 + kk);
            acc2 = fmaf(av.x, w.x, acc2); acc2 = fmaf(av.y, w.y, acc2);
            acc2 = fmaf(av.z, w.z, acc2); acc2 = fmaf(av.w, w.w, acc2);
            w = *(const float4*)(w3 + kk);
            acc3 = fmaf(av.x, w.x, acc3); acc3 = fmaf(av.y, w.y, acc3);
            acc3 = fmaf(av.z, w.z, acc3); acc3 = fmaf(av.w, w.w, acc3);
        }
        __syncthreads();
    }

    red[t][0] = acc0; red[t][1] = acc1; red[t][2] = acc2; red[t][3] = acc3;
    __syncthreads();

    if (t < 64) {
        float tot[4];
        #pragma unroll
        for (int gg = 0; gg < 4; ++gg) {
            const int r = j + (gg << 10);
            tot[gg] = red[t][gg] + red[t + 64][gg] + red[t + 128][gg] + red[t + 192][gg]
                   + bi[r] + bh[r];
        }
        const float ig = 1.f / (1.f + expf(-tot[0]));
        const float fg = 1.f / (1.f + expf(-tot[1]));
        const float gv = tanhf(tot[2]);
        const float og = 1.f / (1.f + expf(-tot[3]));
        const size_t o  = (size_t)b * HID + j;
        const float  cp = Cprev[o];
        const float  cn = fg * cp + ig * gv;
        const float  hn = og * tanhf(cn);
        Cout[o] = cn;
        Hout[o] = hn;
        if (Hout2) Hout2[o] = hn;
    }
}

extern "C" void kernel_launch(void* const* d_in, const int* in_sizes, int n_in,
                              void* d_out, int out_size, void* d_ws, size_t ws_size,
                              hipStream_t stream)
{
    (void)in_sizes; (void)n_in; (void)out_size;

    const int*   x     = (const int*)  d_in[0];
    const float* embed = (const float*)d_in[1];
    const float* Wi0   = (const float*)d_in[2];
    const float* Wh0   = (const float*)d_in[3];
    const float* bi0   = (const float*)d_in[4];
    const float* bh0   = (const float*)d_in[5];
    const float* Wi1   = (const float*)d_in[6];
    const float* Wh1   = (const float*)d_in[7];
    const float* bi1   = (const float*)d_in[8];
    const float* bh1   = (const float*)d_in[9];
    const float* h0in  = (const float*)d_in[10];
    const float* c0in  = (const float*)d_in[11];

    float* out     = (float*)d_out;
    const size_t BH = (size_t)BATCH * HID;              // 32768
    float* outputs = out;                               // (S,1,B,H)
    float* hiddens = out + (size_t)S_LEN * BH;          // (S,L,B,H)
    float* cells   = out + 3 * (size_t)S_LEN * BH;      // (S,L,B,H)
    uint4* ws      = (uint4*)d_ws;

    // ws: 4 groups x (h0 4x16KB + h1 2x16KB) = 384KB | flags 32KB = 425984 B
    bool coop_ok = (ws_size >= 425984);
    if (coop_ok) {
        void* args[] = {
            (void*)&x, (void*)&embed,
            (void*)&Wi0, (void*)&Wh0, (void*)&bi0, (void*)&bh0,
            (void*)&Wi1, (void*)&Wh1, (void*)&bi1, (void*)&bh1,
            (void*)&h0in, (void*)&c0in,
            (void*)&outputs, (void*)&hiddens, (void*)&cells, (void*)&ws
        };
        hipError_t e = hipLaunchCooperativeKernel((void*)lstm_pipe,
                                                  dim3(NBLK), dim3(NTHR), args, 0, stream);
        if (e != hipSuccess) { (void)hipGetLastError(); coop_ok = false; }
    }
    if (!coop_ok) {
        for (int s = 0; s < S_LEN; ++s) {
            const float* Hp0 = s ? hiddens + ((size_t)(s - 1) * 2 + 0) * BH : h0in;
            const float* Cp0 = s ? cells   + ((size_t)(s - 1) * 2 + 0) * BH : c0in;
            float* H0o = hiddens + ((size_t)s * 2 + 0) * BH;
            float* C0o = cells   + ((size_t)s * 2 + 0) * BH;
            lstm_step<<<512, 256, 0, stream>>>(Wi0, Wh0, bi0, bh0,
                                               embed, x + (size_t)s * BATCH, EMB,
                                               Hp0, Cp0, H0o, C0o, nullptr);

            const float* Hp1 = s ? hiddens + ((size_t)(s - 1) * 2 + 1) * BH : h0in + BH;
            const float* Cp1 = s ? cells   + ((size_t)(s - 1) * 2 + 1) * BH : c0in + BH;
            float* H1o = hiddens + ((size_t)s * 2 + 1) * BH;
            float* C1o = cells   + ((size_t)s * 2 + 1) * BH;
            lstm_step<<<512, 256, 0, stream>>>(Wi1, Wh1, bi1, bh1,
                                               H0o, nullptr, HID,
                                               Hp1, Cp1, H1o, C1o, outputs + (size_t)s * BH);
        }
    }
}

// Round 16
// 2945.203 us; speedup vs baseline: 17.4624x; 17.4624x over previous
//
#include <hip/hip_runtime.h>
#include <hip/hip_cooperative_groups.h>

namespace cg = cooperative_groups;

// 2-layer LSTM, S=512, B=32, H=1024, E=512.
// Round 16: REVERT to the round-13 champion (2.874 ms, verified green).
// r14 ((512,4): VGPR capped 64 -> weight spill, FETCH 21.8GB) and
// r15 ((512,2): 2-blocks/CU co-residency cliff -> device hang) proved the
// 4-group split unreliable. This is the verified 2-group configuration:
// 256 blocks (1/CU), per group a private 128-block pipeline (64 L0 + 64 L1),
// r12 protocol (subset polls, 3-barrier L0, ring depth 4/2, full flag1
// guards), register-stationary bf16 weight B-fragments, LLC tile exchange.

#define S_LEN 512
#define BATCH 32
#define HID   1024
#define EMB   512
#define NBLK  256
#define NTHR  512

typedef short  bf16x8 __attribute__((ext_vector_type(8)));
typedef float  f32x4  __attribute__((ext_vector_type(4)));

union U8 { bf16x8 v; unsigned short us[8]; uint4 u4; unsigned long long ull[2]; };

__device__ __forceinline__ unsigned short f2bf(float f) {   // RNE f32->bf16
    unsigned u = __float_as_uint(f);
    u += 0x7fffu + ((u >> 16) & 1u);
    return (unsigned short)(u >> 16);
}

__device__ __forceinline__ uint4 pack8(float4 lo, float4 hi) {
    U8 r;
    r.us[0] = f2bf(lo.x); r.us[1] = f2bf(lo.y); r.us[2] = f2bf(lo.z); r.us[3] = f2bf(lo.w);
    r.us[4] = f2bf(hi.x); r.us[5] = f2bf(hi.y); r.us[6] = f2bf(hi.z); r.us[7] = f2bf(hi.w);
    return r.u4;
}

__device__ __forceinline__ f32x4 mfma16(bf16x8 a, bf16x8 b, f32x4 c) {
    return __builtin_amdgcn_mfma_f32_16x16x32_bf16(a, b, c, 0, 0, 0);
}

// agent-scope (LLC-coherent, L2-bypass) 16B load/store as 2x8B atomics
__device__ __forceinline__ U8 ld_ws16(const uint4* p) {
    const unsigned long long* q = (const unsigned long long*)p;
    U8 r;
    r.ull[0] = __hip_atomic_load(q,     __ATOMIC_RELAXED, __HIP_MEMORY_SCOPE_AGENT);
    r.ull[1] = __hip_atomic_load(q + 1, __ATOMIC_RELAXED, __HIP_MEMORY_SCOPE_AGENT);
    return r;
}
__device__ __forceinline__ void st_ws16(uint4* p, U8 v) {
    unsigned long long* q = (unsigned long long*)p;
    __hip_atomic_store(q,     v.ull[0], __ATOMIC_RELAXED, __HIP_MEMORY_SCOPE_AGENT);
    __hip_atomic_store(q + 1, v.ull[1], __ATOMIC_RELAXED, __HIP_MEMORY_SCOPE_AGENT);
}

__device__ __forceinline__ float sigm(float x) {
    return __builtin_amdgcn_rcpf(1.0f + __expf(-x));
}
__device__ __forceinline__ float tanh_fast(float x) {
    const float xc = fminf(fmaxf(x, -15.f), 15.f);
    const float t  = __expf(2.f * xc);
    return (t - 1.f) * __builtin_amdgcn_rcpf(t + 1.f);
}

// full poll: lane l watches flags[l*16]; exit when ALL >= target
__device__ __forceinline__ void poll64(const int* flags, int target) {
    const int* p = flags + ((threadIdx.x & 63) << 4);
    for (;;) {
        const int v = __hip_atomic_load(p, __ATOMIC_RELAXED, __HIP_MEMORY_SCOPE_AGENT);
        if (__all(v >= target)) break;
        __builtin_amdgcn_s_sleep(1);
    }
}
// subset poll: watch flags[base..base+cnt) (lanes >= cnt duplicate base)
__device__ __forceinline__ void pollsub(const int* flags, int base, int cnt, int target) {
    const int l   = threadIdx.x & 63;
    const int idx = (l < cnt) ? l : 0;
    const int* p  = flags + ((base + idx) << 4);
    for (;;) {
        const int v = __hip_atomic_load(p, __ATOMIC_RELAXED, __HIP_MEMORY_SCOPE_AGENT);
        if (__all(v >= target)) break;
        __builtin_amdgcn_s_sleep(1);
    }
}

__global__ __launch_bounds__(NTHR, 1)
void lstm_pipe(const int* __restrict__ x, const float* __restrict__ embed,
               const float* __restrict__ Wi0, const float* __restrict__ Wh0,
               const float* __restrict__ bi0, const float* __restrict__ bh0,
               const float* __restrict__ Wi1, const float* __restrict__ Wh1,
               const float* __restrict__ bi1, const float* __restrict__ bh1,
               const float* __restrict__ h0in, const float* __restrict__ c0in,
               float* __restrict__ outputs, float* __restrict__ hiddens,
               float* __restrict__ cells, uint4* __restrict__ ws)
{
    __shared__ f32x4 sRed[8][4][64];               // 32KB
    __shared__ uint4 sEmb[64 * 17];                // 17.4KB (L0 only)
    __shared__ float sGates[16][68];
    __shared__ unsigned short sHex[16][16];
    __shared__ float sBias[16][4];

    const int tid  = threadIdx.x;
    const int lane = tid & 63;
    const int wv   = tid >> 6;                     // 0..7 = K-split wave
    const int bx   = blockIdx.x;
    const int grp  = bx >> 7;                      // 0..1 = batch-row group
    const int gbx  = bx & 127;
    const bool isL0 = (gbx < 64);
    const int g    = isL0 ? gbx : gbx - 64;        // column-block id 0..63

    // ws (uint4 units): per group: h0 ring 4x2048 | h1 ring 2x2048 (= 12288)
    // unit = [kg 0..127][b 0..15]: 8 bf16 h-cols kg*8.. for group-row b.
    uint4* h0base = ws + grp * 12288;
    uint4* h1base = h0base + 8192;
    int*   fbase  = (int*)(ws + 24576) + grp * 2048;   // flag0[64],flag1[64] @64B
    int*   flag0  = fbase;
    int*   flag1  = fbase + 1024;

    // ---- prepass: zero flags, init h tiles ----
    {
        const int gt = bx * NTHR + tid;
        if (gt < 4096) ((int*)(ws + 24576))[gt] = 0;
        if (gt < 8192) {                           // 2 grp x 2 layer x 128 kg x 16 b
            const int b = gt & 15, kg8 = (gt >> 4) & 127;
            const int layer = (gt >> 11) & 1, gg = gt >> 12;
            const float* src = h0in + ((size_t)((layer << 5) + (gg << 4) + b)) * HID + (kg8 << 3);
            uint4* dst = ws + gg * 12288 + (layer ? (8192 + 2048) : (3 * 2048));
            dst[(kg8 << 4) + b] = pack8(*(const float4*)src, *(const float4*)(src + 4));
        }
    }
    if (tid < 16) {
        #pragma unroll
        for (int gate = 0; gate < 4; ++gate) {
            const int r = (gate << 10) + (g << 4) + tid;
            sBias[tid][gate] = isL0 ? (bi0[r] + bh0[r]) : (bi1[r] + bh1[r]);
        }
    }
    const int pjj = tid & 15;                      // column (tid<256)
    const int pb  = (tid >> 4) & 15;               // group-local row (tid<256)
    const int jg  = (g << 4) + pjj;
    const int growbase = (grp << 4);               // global row = growbase + pb
    float creg = 0.f;
    if (tid < 256)
        creg = c0in[(size_t)((isL0 ? 0 : BATCH) + growbase + pb) * HID + jg];

    // ---- weight B-fragments into registers (verified layout) ----
    const int n_  = lane & 15;
    const int ko_ = (lane >> 4) << 3;
    const int rb_ = ((n_ >> 2) << 10) + (g << 4) + (n_ & 3);
    bf16x8 w0[4][6];
    bf16x8 w1[4][8];
    if (isL0) {
        #pragma unroll
        for (int nt = 0; nt < 4; ++nt) {
            const int r = rb_ + (nt << 2);
            #pragma unroll
            for (int kf = 0; kf < 6; ++kf) {
                const int k = wv * 192 + kf * 32 + ko_;
                const float* src = (k < EMB) ? Wi0 + (size_t)r * EMB + k
                                             : Wh0 + (size_t)r * HID + (k - EMB);
                U8 t; t.u4 = pack8(*(const float4*)src, *(const float4*)(src + 4));
                w0[nt][kf] = t.v;
            }
        }
    } else {
        #pragma unroll
        for (int nt = 0; nt < 4; ++nt) {
            const int r = rb_ + (nt << 2);
            #pragma unroll
            for (int kf = 0; kf < 8; ++kf) {
                const int k = (wv << 8) + kf * 32 + ko_;
                const float* src = (k < HID) ? Wi1 + (size_t)r * HID + k
                                             : Wh1 + (size_t)r * HID + (k - HID);
                U8 t; t.u4 = pack8(*(const float4*)src, *(const float4*)(src + 4));
                w1[nt][kf] = t.v;
            }
        }
    }

    // ---- L0 prologue: stage sEmb(0); pe = emb(1). rows b = wv, wv+8 ----
    float4 pe[2][2];
    if (isL0) {
        #pragma unroll
        for (int it = 0; it < 2; ++it) {
            const int b = wv + (it << 3);
            const float* src = embed + (size_t)x[growbase + b] * EMB + (lane << 3);
            sEmb[lane * 17 + b] = pack8(*(const float4*)src, *(const float4*)(src + 4));
        }
        #pragma unroll
        for (int it = 0; it < 2; ++it) {
            const int b = wv + (it << 3);
            const float* src = embed + (size_t)x[32 + growbase + b] * EMB + (lane << 3);
            pe[it][0] = *(const float4*)src;
            pe[it][1] = *(const float4*)(src + 4);
        }
    }

    cg::grid_group grid = cg::this_grid();
    grid.sync();                                   // publish prepass, once

    const size_t BH = (size_t)BATCH * HID;

    if (isL0) {
        // ======================= LAYER-0 BLOCKS =======================
        for (int s = 0; s < S_LEN; ++s) {
            // subset poll + h-tile loads (waves 2..7; waves 0-1 pure emb)
            U8 r0[6];
            if (wv >= 2) {
                const int fst = (wv * 6 < 16) ? 16 : wv * 6;
                const int pb0 = (fst - 16) << 1;
                const int pct = ((wv * 6 + 6 - 16) << 1) - pb0;
                pollsub(flag0, pb0, pct, s);       // h0(s-1) fresh: flag0>=s
                const uint4* h0p = h0base + (((s + 3) & 3) << 11);
                #pragma unroll
                for (int kf = 0; kf < 6; ++kf) {
                    const int kfg = wv * 6 + kf;
                    if (kfg >= 16) {
                        const int u = ((((kfg - 16) << 2) + (lane >> 4)) << 4) + (lane & 15);
                        r0[kf] = ld_ws16(&h0p[u]);
                    }
                }
            }
            // MFMA (M=16: single A-frag)
            f32x4 acc[4] = {{0,0,0,0},{0,0,0,0},{0,0,0,0},{0,0,0,0}};
            #pragma unroll
            for (int kf = 0; kf < 6; ++kf) {
                const int kfg = wv * 6 + kf;
                bf16x8 a0;
                if (kfg < 16) {
                    const int u = ((kfg << 2) + (lane >> 4)) * 17 + (lane & 15);
                    U8 t0; t0.u4 = sEmb[u]; a0 = t0.v;
                } else {
                    a0 = r0[kf].v;
                }
                #pragma unroll
                for (int nt = 0; nt < 4; ++nt)
                    acc[nt] = mfma16(a0, w0[nt][kf], acc[nt]);
            }
            #pragma unroll
            for (int nt = 0; nt < 4; ++nt)
                sRed[wv][nt][lane] = acc[nt];
            __syncthreads();                       // B1: sRed ready, sEmb reads done

            // stage sEmb(s+1); issue pe(s+2); reduce  (B1..B2 window)
            if (s + 1 < S_LEN) {
                #pragma unroll
                for (int it = 0; it < 2; ++it)
                    sEmb[lane * 17 + wv + (it << 3)] = pack8(pe[it][0], pe[it][1]);
            }
            if (s + 2 < S_LEN) {
                #pragma unroll
                for (int it = 0; it < 2; ++it) {
                    const int b = wv + (it << 3);
                    const float* src = embed + (size_t)x[((s + 2) << 5) + growbase + b] * EMB + (lane << 3);
                    pe[it][0] = *(const float4*)src;
                    pe[it][1] = *(const float4*)(src + 4);
                }
            }
            if (tid < 256) {                       // K-split reduce (4 tiles)
                const int nt = tid >> 6, l = tid & 63;
                f32x4 sum = sRed[0][nt][l];
                #pragma unroll
                for (int w = 1; w < 8; ++w) sum += sRed[w][nt][l];
                const int b0 = (l >> 4) << 2;
                const int col = (nt << 4) + (l & 15);
                sGates[b0 + 0][col] = sum[0];
                sGates[b0 + 1][col] = sum[1];
                sGates[b0 + 2][col] = sum[2];
                sGates[b0 + 3][col] = sum[3];
            }
            __syncthreads();                       // B2: gates + sEmb(s+1) ready

            float cn_out = 0.f, hn_out = 0.f;
            if (tid < 256) {                       // pointwise (16x16 values)
                const int cb = ((pjj >> 2) << 4) + (pjj & 3);
                const float ii = sigm     (sGates[pb][cb]      + sBias[pjj][0]);
                const float ff = sigm     (sGates[pb][cb + 4]  + sBias[pjj][1]);
                const float gg = tanh_fast(sGates[pb][cb + 8]  + sBias[pjj][2]);
                const float oo = sigm     (sGates[pb][cb + 12] + sBias[pjj][3]);
                cn_out = ff * creg + ii * gg;
                creg = cn_out;
                hn_out = oo * tanh_fast(cn_out);
                sHex[pb][pjj] = f2bf(hn_out);
            }
            __syncthreads();                       // B3: sHex ready

            if (wv == 0) {                         // publish h0(s)
                if (s >= 4) poll64(flag1, s - 3);  // FULL ring-overwrite guard
                if (lane < 32) {
                    const int b = lane & 15, kgl = lane >> 4;
                    U8 hb;
                    #pragma unroll
                    for (int jj = 0; jj < 8; ++jj) hb.us[jj] = sHex[b][(kgl << 3) + jj];
                    st_ws16(h0base + ((s & 3) << 11) + ((((g << 1) + kgl)) << 4) + b, hb);
                }
                asm volatile("s_waitcnt vmcnt(0)" ::: "memory");
                if (lane == 0)
                    __hip_atomic_store(flag0 + (g << 4), s + 1,
                                       __ATOMIC_RELAXED, __HIP_MEMORY_SCOPE_AGENT);
            }
            // d_out off the critical path
            if (tid < 256) {
                const size_t o = (size_t)(growbase + pb) * HID + jg;
                cells  [(size_t)(s << 1) * BH + o] = cn_out;
                hiddens[(size_t)(s << 1) * BH + o] = hn_out;
            }
        }
    } else {
        // ======================= LAYER-1 BLOCKS =======================
        for (int s = 0; s < S_LEN; ++s) {
            // waves 0-3: subset poll of their 16 h0 publishers;
            // waves 4-7: FULL flag1 poll (depth-2 h1 overwrite proof)
            if (wv < 4) pollsub(flag0, wv << 4, 16, s + 1);
            else        poll64(flag1, s);

            const uint4* h0c = h0base + ((s & 3) << 11);
            const uint4* h1p = h1base + (((s + 1) & 1) << 11);
            U8 r0[8];
            #pragma unroll
            for (int kf = 0; kf < 8; ++kf) {
                const int kfg = (wv << 3) + kf;
                const uint4* src = (kfg < 32) ? h0c : h1p;
                const int u = ((((kfg & 31) << 2) + (lane >> 4)) << 4) + (lane & 15);
                r0[kf] = ld_ws16(&src[u]);
            }
            f32x4 acc[4] = {{0,0,0,0},{0,0,0,0},{0,0,0,0},{0,0,0,0}};
            #pragma unroll
            for (int kf = 0; kf < 8; ++kf) {
                #pragma unroll
                for (int nt = 0; nt < 4; ++nt)
                    acc[nt] = mfma16(r0[kf].v, w1[nt][kf], acc[nt]);
            }
            #pragma unroll
            for (int nt = 0; nt < 4; ++nt)
                sRed[wv][nt][lane] = acc[nt];
            __syncthreads();
            if (tid < 256) {
                const int nt = tid >> 6, l = tid & 63;
                f32x4 sum = sRed[0][nt][l];
                #pragma unroll
                for (int w = 1; w < 8; ++w) sum += sRed[w][nt][l];
                const int b0 = (l >> 4) << 2;
                const int col = (nt << 4) + (l & 15);
                sGates[b0 + 0][col] = sum[0];
                sGates[b0 + 1][col] = sum[1];
                sGates[b0 + 2][col] = sum[2];
                sGates[b0 + 3][col] = sum[3];
            }
            __syncthreads();
            float cn_out = 0.f, hn_out = 0.f;
            if (tid < 256) {                       // pointwise
                const int cb = ((pjj >> 2) << 4) + (pjj & 3);
                const float ii = sigm     (sGates[pb][cb]      + sBias[pjj][0]);
                const float ff = sigm     (sGates[pb][cb + 4]  + sBias[pjj][1]);
                const float gg = tanh_fast(sGates[pb][cb + 8]  + sBias[pjj][2]);
                const float oo = sigm     (sGates[pb][cb + 12] + sBias[pjj][3]);
                cn_out = ff * creg + ii * gg;
                creg = cn_out;
                hn_out = oo * tanh_fast(cn_out);
                sHex[pb][pjj] = f2bf(hn_out);
            }
            __syncthreads();
            if (wv == 0) {                         // publish h1(s)
                if (lane < 32) {
                    const int b = lane & 15, kgl = lane >> 4;
                    U8 hb;
                    #pragma unroll
                    for (int jj = 0; jj < 8; ++jj) hb.us[jj] = sHex[b][(kgl << 3) + jj];
                    st_ws16(h1base + ((s & 1) << 11) + ((((g << 1) + kgl)) << 4) + b, hb);
                }
                asm volatile("s_waitcnt vmcnt(0)" ::: "memory");
                if (lane == 0)
                    __hip_atomic_store(flag1 + (g << 4), s + 1,
                                       __ATOMIC_RELAXED, __HIP_MEMORY_SCOPE_AGENT);
            }
            // d_out off the critical path
            if (tid < 256) {
                const size_t o = (size_t)(growbase + pb) * HID + jg;
                cells  [(size_t)((s << 1) + 1) * BH + o] = cn_out;
                hiddens[(size_t)((s << 1) + 1) * BH + o] = hn_out;
                outputs[(size_t)s * BH + o]              = hn_out;
            }
        }
    }
}

// ---------------- fallback: verified round-0 per-step kernel ----------------
#define KC 256
__global__ __launch_bounds__(256)
void lstm_step(const float* __restrict__ Wi, const float* __restrict__ Wh,
               const float* __restrict__ bi, const float* __restrict__ bh,
               const float* __restrict__ xsrc, const int* __restrict__ xidx, int K1,
               const float* __restrict__ Hprev, const float* __restrict__ Cprev,
               float* __restrict__ Hout, float* __restrict__ Cout,
               float* __restrict__ Hout2)
{
    __shared__ float As[32][KC + 4];
    __shared__ float red[256][5];

    const int t  = threadIdx.x;
    const int b  = t & 31;
    const int jl = (t >> 5) & 1;
    const int ks = t >> 6;
    const int j  = (blockIdx.x << 1) + jl;

    const int Ktot = K1 + HID;
    const int NC   = Ktot / KC;

    float acc0 = 0.f, acc1 = 0.f, acc2 = 0.f, acc3 = 0.f;

    for (int c = 0; c < NC; ++c) {
        const int  k0  = c * KC;
        const bool isX = (k0 < K1);

        #pragma unroll
        for (int i = 0; i < 8; ++i) {
            const int idx4 = t + (i << 8);
            const int row  = idx4 >> 6;
            const int c4   = idx4 & 63;
            const float* src;
            if (isX) {
                const size_t r0 = xidx ? (size_t)xidx[row] : (size_t)row;
                src = xsrc + r0 * (size_t)K1 + k0;
            } else {
                src = Hprev + (size_t)row * HID + (k0 - K1);
            }
            *(float4*)&As[row][c4 << 2] = *(const float4*)(src + (c4 << 2));
        }
        __syncthreads();

        const float* W      = isX ? Wi : Wh;
        const int    stride = isX ? K1 : HID;
        const int    kw     = k0 + (ks << 6) - (isX ? 0 : K1);
        const float* w0 = W + (size_t)(j       ) * stride + kw;
        const float* w1 = W + (size_t)(j + 1024) * stride + kw;
        const float* w2 = W + (size_t)(j + 2048) * stride + kw;
        const float* w3 = W + (size_t)(j + 3072) * stride + kw;
        const float* a  = &As[b][ks << 6];

        #pragma unroll 4
        for (int kk = 0; kk < 64; kk += 4) {
            const float4 av = *(const float4*)(a + kk);
            float4 w;
            w = *(const float4*)(w0 + kk);
            acc0 = fmaf(av.x, w.x, acc0); acc0 = fmaf(av.y, w.y, acc0);
            acc0 = fmaf(av.z, w.z, acc0); acc0 = fmaf(av.w, w.w, acc0);
            w = *(const float4*)(w1 + kk);
            acc1 = fmaf(av.x, w.x, acc1); acc1 = fmaf(av.y, w.y, acc1);
            acc1 = fmaf(av.z, w.z, acc1); acc1 = fmaf(av.w, w.w, acc1);
            w = *(const float4*)(w2 + kk);
            acc2 = fmaf(av.x, w.x, acc2); acc2 = fmaf(av.y, w.y, acc2);
            acc2 = fmaf(av.z, w.z, acc2); acc2 = fmaf(av.w, w.w, acc2);
            w = *(const float4*)(w3 + kk);
            acc3 = fmaf(av.x, w.x, acc3); acc3 = fmaf(av.y, w.y, acc3);
            acc3 = fmaf(av.z, w.z, acc3); acc3 = fmaf(av.w, w.w, acc3);
        }
        __syncthreads();
    }

    red[t][0] = acc0; red[t][1] = acc1; red[t][2] = acc2; red[t][3] = acc3;
    __syncthreads();

    if (t < 64) {
        float tot[4];
        #pragma unroll
        for (int gg = 0; gg < 4; ++gg) {
            const int r = j + (gg << 10);
            tot[gg] = red[t][gg] + red[t + 64][gg] + red[t + 128][gg] + red[t + 192][gg]
                   + bi[r] + bh[r];
        }
        const float ig = 1.f / (1.f + expf(-tot[0]));
        const float fg = 1.f / (1.f + expf(-tot[1]));
        const float gv = tanhf(tot[2]);
        const float og = 1.f / (1.f + expf(-tot[3]));
        const size_t o  = (size_t)b * HID + j;
        const float  cp = Cprev[o];
        const float  cn = fg * cp + ig * gv;
        const float  hn = og * tanhf(cn);
        Cout[o] = cn;
        Hout[o] = hn;
        if (Hout2) Hout2[o] = hn;
    }
}

extern "C" void kernel_launch(void* const* d_in, const int* in_sizes, int n_in,
                              void* d_out, int out_size, void* d_ws, size_t ws_size,
                              hipStream_t stream)
{
    (void)in_sizes; (void)n_in; (void)out_size;

    const int*   x     = (const int*)  d_in[0];
    const float* embed = (const float*)d_in[1];
    const float* Wi0   = (const float*)d_in[2];
    const float* Wh0   = (const float*)d_in[3];
    const float* bi0   = (const float*)d_in[4];
    const float* bh0   = (const float*)d_in[5];
    const float* Wi1   = (const float*)d_in[6];
    const float* Wh1   = (const float*)d_in[7];
    const float* bi1   = (const float*)d_in[8];
    const float* bh1   = (const float*)d_in[9];
    const float* h0in  = (const float*)d_in[10];
    const float* c0in  = (const float*)d_in[11];

    float* out     = (float*)d_out;
    const size_t BH = (size_t)BATCH * HID;              // 32768
    float* outputs = out;                               // (S,1,B,H)
    float* hiddens = out + (size_t)S_LEN * BH;          // (S,L,B,H)
    float* cells   = out + 3 * (size_t)S_LEN * BH;      // (S,L,B,H)
    uint4* ws      = (uint4*)d_ws;

    // ws: 2 groups x (h0 4x32KB + h1 2x32KB) = 384KB | flags 16KB = 409600 B
    bool coop_ok = (ws_size >= 409600);
    if (coop_ok) {
        void* args[] = {
            (void*)&x, (void*)&embed,
            (void*)&Wi0, (void*)&Wh0, (void*)&bi0, (void*)&bh0,
            (void*)&Wi1, (void*)&Wh1, (void*)&bi1, (void*)&bh1,
            (void*)&h0in, (void*)&c0in,
            (void*)&outputs, (void*)&hiddens, (void*)&cells, (void*)&ws
        };
        hipError_t e = hipLaunchCooperativeKernel((void*)lstm_pipe,
                                                  dim3(NBLK), dim3(NTHR), args, 0, stream);
        if (e != hipSuccess) { (void)hipGetLastError(); coop_ok = false; }
    }
    if (!coop_ok) {
        for (int s = 0; s < S_LEN; ++s) {
            const float* Hp0 = s ? hiddens + ((size_t)(s - 1) * 2 + 0) * BH : h0in;
            const float* Cp0 = s ? cells   + ((size_t)(s - 1) * 2 + 0) * BH : c0in;
            float* H0o = hiddens + ((size_t)s * 2 + 0) * BH;
            float* C0o = cells   + ((size_t)s * 2 + 0) * BH;
            lstm_step<<<512, 256, 0, stream>>>(Wi0, Wh0, bi0, bh0,
                                               embed, x + (size_t)s * BATCH, EMB,
                                               Hp0, Cp0, H0o, C0o, nullptr);

            const float* Hp1 = s ? hiddens + ((size_t)(s - 1) * 2 + 1) * BH : h0in + BH;
            const float* Cp1 = s ? cells   + ((size_t)(s - 1) * 2 + 1) * BH : c0in + BH;
            float* H1o = hiddens + ((size_t)s * 2 + 1) * BH;
            float* C1o = cells   + ((size_t)s * 2 + 1) * BH;
            lstm_step<<<512, 256, 0, stream>>>(Wi1, Wh1, bi1, bh1,
                                               H0o, nullptr, HID,
                                               Hp1, Cp1, H1o, C1o, outputs + (size_t)s * BH);
        }
    }
}